// Round 23
// baseline (505.370 us; speedup 1.0000x reference)
//
#include <hip/hip_runtime.h>
#include <cstdint>
#include <cstddef>

#define GXd 480
#define GYd 360
#define NBd 2
#define GXY (480*360)
#define NCELL (NBd*GXY)
#define EPSBN 1e-5f

typedef float  f32x4  __attribute__((ext_vector_type(4)));
typedef short  bf16x8 __attribute__((ext_vector_type(8)));

// ---------- order-preserving float <-> uint map (residual atomics only) ----------
__device__ __forceinline__ unsigned mapf(float f){
    unsigned u = __float_as_uint(f);
    return (u & 0x80000000u) ? ~u : (u | 0x80000000u);
}
__device__ __forceinline__ float unmapf(unsigned m){
    return (m & 0x80000000u) ? __uint_as_float(m ^ 0x80000000u)
                             : __uint_as_float(~m);
}

// ---------- bf16 helpers ----------
__device__ __forceinline__ unsigned short f2bf(float f){            // RTN-even
    unsigned u = __float_as_uint(f);
    unsigned r = (u + 0x7FFFu + ((u >> 16) & 1u)) >> 16;
    return (unsigned short)r;
}
__device__ __forceinline__ float bf2f(unsigned short s){
    return __uint_as_float(((unsigned)s) << 16);
}

// ---------- dense layer helper ----------
template<int DIN, int DOUT>
__device__ __forceinline__ void dense(const float (&in)[DIN], float (&out)[DOUT],
                                      const float* __restrict__ w,
                                      const float* __restrict__ b){
#pragma unroll
    for (int j = 0; j < DOUT; j++) out[j] = b[j];
#pragma unroll
    for (int d = 0; d < DIN; d++){
        float v = in[d];
#pragma unroll
        for (int j = 0; j < DOUT; j++) out[j] = fmaf(v, w[d*DOUT + j], out[j]);
    }
}

// ---------- block-level sum/sumsq reduction ----------
template<int D>
__device__ __forceinline__ void reduce_stats(const float (&h)[D], bool valid,
                                             float* __restrict__ gsum,
                                             float* __restrict__ gsq){
    __shared__ float ssum[D];
    __shared__ float ssq[D];
    int tid = threadIdx.x;
    for (int t = tid; t < D; t += 256){ ssum[t] = 0.f; ssq[t] = 0.f; }
    __syncthreads();
#pragma unroll
    for (int j = 0; j < D; j++){
        float v = valid ? h[j] : 0.f;
        float s = v * v;
#pragma unroll
        for (int o = 32; o > 0; o >>= 1){
            v += __shfl_down(v, o, 64);
            s += __shfl_down(s, o, 64);
        }
        if ((tid & 63) == 0){
            atomicAdd(&ssum[j], v);
            atomicAdd(&ssq[j], s);
        }
    }
    __syncthreads();
    for (int t = tid; t < D; t += 256){
        atomicAdd(&gsum[t], ssum[t]);
        atomicAdd(&gsq[t], ssq[t]);
    }
}

// ---------- BN coefficient from sums (inline finalize) ----------
__device__ __forceinline__ void bn_coef(const float* __restrict__ sum,
                                        const float* __restrict__ sq,
                                        const float* __restrict__ g,
                                        const float* __restrict__ bb,
                                        float invN, int c,
                                        float* __restrict__ a_out,
                                        float* __restrict__ c_out){
    float mu  = sum[c] * invN;
    float var = fmaf(-mu, mu, sq[c] * invN);
    float rs  = rsqrtf(var + EPSBN);
    float a   = rs * g[c];
    a_out[c] = a;
    c_out[c] = fmaf(-mu, a, bb[c]);
}

// ---------- stats of raw input columns 0..8 ----------
__global__ __launch_bounds__(256)
void k_stats0(const float* __restrict__ fea, float* gsum, float* gsq, int n){
    int i = blockIdx.x*256 + threadIdx.x;
    bool valid = i < n;
    int i2 = valid ? i : 0;
    float x[9];
#pragma unroll
    for (int d = 0; d < 9; d++) x[d] = fea[(size_t)i2*11 + d];
    reduce_stats<9>(x, valid, gsum, gsq);
}

// ---------- layer1: bn0 (inline fin) -> 9x32; z1 bf16; stats(rounded); cnt/rank; res ----------
__global__ __launch_bounds__(256)
void k_l1(const float* __restrict__ fea, const int* __restrict__ ind,
          const float* __restrict__ w1, const float* __restrict__ b1,
          const float* __restrict__ sum0, const float* __restrict__ sq0,
          const float* __restrict__ g0, const float* __restrict__ bb0, float invN,
          unsigned short* __restrict__ z1, unsigned* __restrict__ pres,
          unsigned* __restrict__ cnt, unsigned* __restrict__ rank,
          float* gsum, float* gsq, int n){
    __shared__ float a0s[9], c0s[9];
    int tid = threadIdx.x;
    if (tid < 9) bn_coef(sum0, sq0, g0, bb0, invN, tid, a0s, c0s);
    __syncthreads();

    int i = blockIdx.x*256 + tid;
    bool valid = i < n;
    int i2 = valid ? i : 0;
    float x[9];
#pragma unroll
    for (int d = 0; d < 9; d++) x[d] = fmaf(fea[(size_t)i2*11 + d], a0s[d], c0s[d]);
    float h[32];
    dense<9,32>(x, h, w1, b1);
    unsigned ob[16];
#pragma unroll
    for (int m = 0; m < 16; m++){
        unsigned short lo = f2bf(h[2*m]);
        unsigned short hi = f2bf(h[2*m+1]);
        ob[m] = (unsigned)lo | ((unsigned)hi << 16);
        h[2*m]   = bf2f(lo);
        h[2*m+1] = bf2f(hi);
    }
    if (valid){
        uint4* dst = (uint4*)(z1 + (size_t)i*32);
#pragma unroll
        for (int q = 0; q < 4; q++)
            dst[q] = make_uint4(ob[q*4], ob[q*4+1], ob[q*4+2], ob[q*4+3]);
        float r0 = fea[(size_t)i*11 + 9];
        float r1 = fea[(size_t)i*11 + 10];
        int bb = ind[(size_t)i*3 + 0];
        int gx = ind[(size_t)i*3 + 1];
        int gy = ind[(size_t)i*3 + 2];
        unsigned vox = ((unsigned)bb*GXd + (unsigned)gx)*GYd + (unsigned)gy;
        rank[i] = atomicAdd(&cnt[vox], 1u);
        size_t rbase = (size_t)bb*2*GXY + (size_t)gx*GYd + gy;
        atomicMax(pres + rbase,       mapf(r0));
        atomicMax(pres + rbase + GXY, mapf(r1));
    }
    reduce_stats<32>(h, valid, gsum, gsq);
}

// ---------- layer2 via MFMA (8 row-groups/block): z2 bf16; stats(rounded) ----------
__global__ __launch_bounds__(256)
void k_l2(const unsigned short* __restrict__ z1,
          const float* __restrict__ w2, const float* __restrict__ b2,
          const float* __restrict__ sum1, const float* __restrict__ sq1,
          const float* __restrict__ g1, const float* __restrict__ bb1, float invN,
          unsigned short* __restrict__ z2, float* gsum, float* gsq, int n){
    __shared__ short w2t[64*40];
    __shared__ float a1s[32], c1s[32];
    __shared__ float ssum[64], ssq[64];
    int tid = threadIdx.x;
    if (tid < 64){ ssum[tid] = 0.f; ssq[tid] = 0.f; }
    if (tid < 32) bn_coef(sum1, sq1, g1, bb1, invN, tid, a1s, c1s);
    for (int e = tid; e < 2048; e += 256){
        int k = e >> 6, c = e & 63;
        w2t[c*40 + k] = (short)f2bf(w2[k*64 + c]);
    }
    __syncthreads();

    int lane = tid & 63, wid = tid >> 6;
    int l15 = lane & 15, lg = lane >> 4;
    int kbase = lg*8;
    float4 av0 = *(const float4*)&a1s[kbase];
    float4 av1 = *(const float4*)&a1s[kbase + 4];
    float4 cv0 = *(const float4*)&c1s[kbase];
    float4 cv1 = *(const float4*)&c1s[kbase + 4];

#pragma unroll 1
    for (int rg = 0; rg < 8; rg++){
        int p0 = blockIdx.x*512 + rg*64 + wid*16;
        int prow = p0 + l15;
        int prow2 = prow < n ? prow : (n - 1);
        uint4 ua = *(const uint4*)(z1 + (size_t)prow2*32 + kbase);
        bf16x8 af;
        af[0] = (short)f2bf(fmaxf(fmaf(bf2f((unsigned short)(ua.x & 0xFFFFu)), av0.x, cv0.x), 0.f));
        af[1] = (short)f2bf(fmaxf(fmaf(bf2f((unsigned short)(ua.x >> 16)),     av0.y, cv0.y), 0.f));
        af[2] = (short)f2bf(fmaxf(fmaf(bf2f((unsigned short)(ua.y & 0xFFFFu)), av0.z, cv0.z), 0.f));
        af[3] = (short)f2bf(fmaxf(fmaf(bf2f((unsigned short)(ua.y >> 16)),     av0.w, cv0.w), 0.f));
        af[4] = (short)f2bf(fmaxf(fmaf(bf2f((unsigned short)(ua.z & 0xFFFFu)), av1.x, cv1.x), 0.f));
        af[5] = (short)f2bf(fmaxf(fmaf(bf2f((unsigned short)(ua.z >> 16)),     av1.y, cv1.y), 0.f));
        af[6] = (short)f2bf(fmaxf(fmaf(bf2f((unsigned short)(ua.w & 0xFFFFu)), av1.z, cv1.z), 0.f));
        af[7] = (short)f2bf(fmaxf(fmaf(bf2f((unsigned short)(ua.w >> 16)),     av1.w, cv1.w), 0.f));

        f32x4 acc[4];
#pragma unroll
        for (int t = 0; t < 4; t++){
            float bv = b2[t*16 + l15];
            acc[t] = (f32x4){bv, bv, bv, bv};
        }
#pragma unroll
        for (int t = 0; t < 4; t++){
            bf16x8 bf = *(const bf16x8*)&w2t[(t*16 + l15)*40 + kbase];
            acc[t] = __builtin_amdgcn_mfma_f32_16x16x32_bf16(af, bf, acc[t], 0, 0, 0);
        }

#pragma unroll
        for (int t = 0; t < 4; t++){
            int c = t*16 + l15;
            float s = 0.f, q = 0.f;
#pragma unroll
            for (int r = 0; r < 4; r++){
                int pr = p0 + lg*4 + r;
                unsigned short rb = f2bf(acc[t][r]);
                float rv = bf2f(rb);
                if (pr < n){
                    z2[(size_t)pr*64 + c] = rb;
                    s += rv; q += rv*rv;
                }
            }
            s += __shfl_xor(s, 16, 64);  q += __shfl_xor(q, 16, 64);
            s += __shfl_xor(s, 32, 64);  q += __shfl_xor(q, 32, 64);
            if (lg == 0){ atomicAdd(&ssum[c], s); atomicAdd(&ssq[c], q); }
        }
    }
    __syncthreads();
    if (tid < 64){ atomicAdd(gsum + tid, ssum[tid]); atomicAdd(gsq + tid, ssq[tid]); }
}

// ---------- layer3 via MFMA (8 row-groups/block): z3 bf16; stats(rounded) ----------
__global__ __launch_bounds__(256)
void k_l3(const unsigned short* __restrict__ z2,
          const float* __restrict__ w3, const float* __restrict__ b3,
          const float* __restrict__ sum2, const float* __restrict__ sq2,
          const float* __restrict__ g2, const float* __restrict__ bb2, float invN,
          unsigned short* __restrict__ z3, float* gsum, float* gsq, int n){
    __shared__ short w3t[128*72];
    __shared__ float a2s[64], c2s[64];
    __shared__ float ssum[128], ssq[128];
    int tid = threadIdx.x;
    if (tid < 128){ ssum[tid] = 0.f; ssq[tid] = 0.f; }
    if (tid < 64) bn_coef(sum2, sq2, g2, bb2, invN, tid, a2s, c2s);
    for (int e = tid; e < 8192; e += 256){
        int k = e >> 7, c = e & 127;
        w3t[c*72 + k] = (short)f2bf(w3[k*128 + c]);
    }
    __syncthreads();

    int lane = tid & 63, wid = tid >> 6;
    int l15 = lane & 15, lg = lane >> 4;

#pragma unroll 1
    for (int rg = 0; rg < 8; rg++){
        int p0 = blockIdx.x*512 + rg*64 + wid*16;
        int prow = p0 + l15;
        int prow2 = prow < n ? prow : (n - 1);
        const unsigned short* zrow = z2 + (size_t)prow2*64;

        f32x4 acc[8];
#pragma unroll
        for (int t = 0; t < 8; t++){
            float bv = b3[t*16 + l15];
            acc[t] = (f32x4){bv, bv, bv, bv};
        }

#pragma unroll
        for (int ks = 0; ks < 2; ks++){
            int kbase = ks*32 + lg*8;
            uint4 ua = *(const uint4*)(zrow + kbase);
            float4 av0 = *(const float4*)&a2s[kbase];
            float4 av1 = *(const float4*)&a2s[kbase + 4];
            float4 cv0 = *(const float4*)&c2s[kbase];
            float4 cv1 = *(const float4*)&c2s[kbase + 4];
            bf16x8 af;
            af[0] = (short)f2bf(fmaxf(fmaf(bf2f((unsigned short)(ua.x & 0xFFFFu)), av0.x, cv0.x), 0.f));
            af[1] = (short)f2bf(fmaxf(fmaf(bf2f((unsigned short)(ua.x >> 16)),     av0.y, cv0.y), 0.f));
            af[2] = (short)f2bf(fmaxf(fmaf(bf2f((unsigned short)(ua.y & 0xFFFFu)), av0.z, cv0.z), 0.f));
            af[3] = (short)f2bf(fmaxf(fmaf(bf2f((unsigned short)(ua.y >> 16)),     av0.w, cv0.w), 0.f));
            af[4] = (short)f2bf(fmaxf(fmaf(bf2f((unsigned short)(ua.z & 0xFFFFu)), av1.x, cv1.x), 0.f));
            af[5] = (short)f2bf(fmaxf(fmaf(bf2f((unsigned short)(ua.z >> 16)),     av1.y, cv1.y), 0.f));
            af[6] = (short)f2bf(fmaxf(fmaf(bf2f((unsigned short)(ua.w & 0xFFFFu)), av1.z, cv1.z), 0.f));
            af[7] = (short)f2bf(fmaxf(fmaf(bf2f((unsigned short)(ua.w >> 16)),     av1.w, cv1.w), 0.f));
#pragma unroll
            for (int t = 0; t < 8; t++){
                bf16x8 bf = *(const bf16x8*)&w3t[(t*16 + l15)*72 + kbase];
                acc[t] = __builtin_amdgcn_mfma_f32_16x16x32_bf16(af, bf, acc[t], 0, 0, 0);
            }
        }

#pragma unroll
        for (int t = 0; t < 8; t++){
            int c = t*16 + l15;
            float s = 0.f, q = 0.f;
#pragma unroll
            for (int r = 0; r < 4; r++){
                int pr = p0 + lg*4 + r;
                unsigned short rb = f2bf(acc[t][r]);
                float rv = bf2f(rb);
                if (pr < n){
                    z3[(size_t)pr*128 + c] = rb;
                    s += rv; q += rv*rv;
                }
            }
            s += __shfl_xor(s, 16, 64);  q += __shfl_xor(q, 16, 64);
            s += __shfl_xor(s, 32, 64);  q += __shfl_xor(q, 32, 64);
            if (lg == 0){ atomicAdd(&ssum[c], s); atomicAdd(&ssq[c], q); }
        }
    }
    __syncthreads();
    if (tid < 128){ atomicAdd(gsum + tid, ssum[tid]); atomicAdd(gsq + tid, ssq[tid]); }
}

// ---------- exclusive scan of cnt via block tickets ----------
__global__ __launch_bounds__(256)
void k_off(const unsigned* __restrict__ cnt, unsigned* __restrict__ off,
           unsigned* __restrict__ gctr){
    __shared__ unsigned wtot[4];
    __shared__ unsigned wbase[4];
    int t = threadIdx.x;
    int lane = t & 63, w = t >> 6;
    int base = blockIdx.x * 1024 + t * 4;
    bool ok = base < NCELL;
    unsigned c0 = 0, c1 = 0, c2 = 0, c3 = 0;
    if (ok){ c0 = cnt[base]; c1 = cnt[base+1]; c2 = cnt[base+2]; c3 = cnt[base+3]; }
    unsigned tot = c0 + c1 + c2 + c3;
    unsigned incl = tot;
#pragma unroll
    for (int o = 1; o < 64; o <<= 1){
        unsigned v = __shfl_up(incl, o, 64);
        if (lane >= o) incl += v;
    }
    if (lane == 63) wtot[w] = incl;
    __syncthreads();
    if (t == 0){
        unsigned bt = wtot[0] + wtot[1] + wtot[2] + wtot[3];
        unsigned gb = atomicAdd(gctr, bt);
        unsigned s = 0;
#pragma unroll
        for (int q = 0; q < 4; q++){ wbase[q] = gb + s; s += wtot[q]; }
    }
    __syncthreads();
    if (ok){
        unsigned tb = wbase[w] + incl - tot;
        off[base]   = tb;
        off[base+1] = tb + c0;
        off[base+2] = tb + c0 + c1;
        off[base+3] = tb + c0 + c1 + c2;
    }
}

// ---------- fill per-cell point lists ----------
__global__ __launch_bounds__(256)
void k_fill(const int* __restrict__ ind, const unsigned* __restrict__ rank,
            const unsigned* __restrict__ off, unsigned* __restrict__ list, int n){
    int i = blockIdx.x*256 + threadIdx.x;
    if (i >= n) return;
    int bb = ind[(size_t)i*3], gx = ind[(size_t)i*3+1], gy = ind[(size_t)i*3+2];
    unsigned vox = ((unsigned)bb*GXd + (unsigned)gx)*GYd + (unsigned)gy;
    list[off[vox] + rank[i]] = (unsigned)i;
}

// ---------- layer4 via MFMA (8 row-groups/block), SORTED output ----------
__global__ __launch_bounds__(256)
void k_l4(const unsigned short* __restrict__ z3, const unsigned* __restrict__ list,
          const float* __restrict__ w4, const float* __restrict__ b4,
          const float* __restrict__ sum3, const float* __restrict__ sq3,
          const float* __restrict__ g3, const float* __restrict__ bb3, float invN,
          unsigned short* __restrict__ z4, int n){
    __shared__ short w4t[256*128];           // 64 KB
    __shared__ float a3s[128], c3s[128];
    int tid = threadIdx.x;
    if (tid < 128) bn_coef(sum3, sq3, g3, bb3, invN, tid, a3s, c3s);
    for (int e = tid; e < 16384; e += 256){
        int k2 = e >> 8;
        int c  = e & 255;
        unsigned lo = f2bf(w4[(size_t)(2*k2)*256 + c]);
        unsigned hi = f2bf(w4[(size_t)(2*k2+1)*256 + c]);
        int addr = (c*256 + k2*4) ^ ((c & 7) << 4);
        *(unsigned*)((char*)w4t + addr) = lo | (hi << 16);
    }
    __syncthreads();

    int lane = tid & 63, wid = tid >> 6;
    int l15 = lane & 15, lg = lane >> 4;

#pragma unroll 1
    for (int rg = 0; rg < 8; rg++){
        int p0 = blockIdx.x*512 + rg*64 + wid*16;
        int prow = p0 + l15;
        int prow2 = prow < n ? prow : (n - 1);
        int srow = (int)list[prow2];
        const unsigned short* zrow = z3 + (size_t)srow*128;

        f32x4 acc[16];
#pragma unroll
        for (int t = 0; t < 16; t++){
            float bv = b4[t*16 + l15];
            acc[t] = (f32x4){bv, bv, bv, bv};
        }

#pragma unroll
        for (int ks = 0; ks < 4; ks++){
            int kbase = ks*32 + lg*8;
            uint4 ua = *(const uint4*)(zrow + kbase);
            float4 av0 = *(const float4*)&a3s[kbase];
            float4 av1 = *(const float4*)&a3s[kbase + 4];
            float4 cv0 = *(const float4*)&c3s[kbase];
            float4 cv1 = *(const float4*)&c3s[kbase + 4];
            bf16x8 af;
            af[0] = (short)f2bf(fmaxf(fmaf(bf2f((unsigned short)(ua.x & 0xFFFFu)), av0.x, cv0.x), 0.f));
            af[1] = (short)f2bf(fmaxf(fmaf(bf2f((unsigned short)(ua.x >> 16)),     av0.y, cv0.y), 0.f));
            af[2] = (short)f2bf(fmaxf(fmaf(bf2f((unsigned short)(ua.y & 0xFFFFu)), av0.z, cv0.z), 0.f));
            af[3] = (short)f2bf(fmaxf(fmaf(bf2f((unsigned short)(ua.y >> 16)),     av0.w, cv0.w), 0.f));
            af[4] = (short)f2bf(fmaxf(fmaf(bf2f((unsigned short)(ua.z & 0xFFFFu)), av1.x, cv1.x), 0.f));
            af[5] = (short)f2bf(fmaxf(fmaf(bf2f((unsigned short)(ua.z >> 16)),     av1.y, cv1.y), 0.f));
            af[6] = (short)f2bf(fmaxf(fmaf(bf2f((unsigned short)(ua.w & 0xFFFFu)), av1.z, cv1.z), 0.f));
            af[7] = (short)f2bf(fmaxf(fmaf(bf2f((unsigned short)(ua.w >> 16)),     av1.w, cv1.w), 0.f));
#pragma unroll
            for (int t = 0; t < 16; t++){
                int c = t*16 + l15;
                int addr = (c*256 + kbase*2) ^ ((c & 7) << 4);
                bf16x8 bf = *(const bf16x8*)((const char*)w4t + addr);
                acc[t] = __builtin_amdgcn_mfma_f32_16x16x32_bf16(af, bf, acc[t], 0, 0, 0);
            }
        }

#pragma unroll
        for (int t = 0; t < 16; t++){
#pragma unroll
            for (int r = 0; r < 4; r++){
                int pr = p0 + lg*4 + r;
                if (pr < n)
                    z4[(size_t)pr*256 + t*16 + l15] = f2bf(acc[t][r]);
            }
        }
    }
}

// ---------- FUSED gather-max + 3x3 maxpool + residual, CHANNEL-SPLIT, 8-deep staging ----------
#define NOCELL 0xFFFFFFFFu
#define OTS 132
__global__ __launch_bounds__(256, 5)
void k_gpool(const unsigned* __restrict__ cnt, const unsigned* __restrict__ off,
             const unsigned short* __restrict__ z4, const unsigned* __restrict__ pres,
             float* __restrict__ out){
    __shared__ unsigned short cm[6*18*128];   // 27648 B
    __shared__ unsigned cno[216];
    int t = threadIdx.x;
    int gy0 = blockIdx.x * 16;
    int gx0 = blockIdx.y * 4;
    int bz  = blockIdx.z;
    int b   = bz >> 1;
    int ch0 = (bz & 1) * 128;
    int ymax = GYd - gy0; if (ymax > 16) ymax = 16;

    for (int e = t; e < 108; e += 256){
        int xx = e / 18, ty = e % 18;
        int gxx = gx0 - 1 + xx, gyy = gy0 - 1 + ty;
        unsigned c = NOCELL, o = 0;
        if ((unsigned)gxx < (unsigned)GXd && (unsigned)gyy < (unsigned)GYd){
            unsigned cell = ((unsigned)b*GXd + gxx)*GYd + gyy;
            c = cnt[cell]; o = off[cell];
        }
        cno[e*2]   = c;
        cno[e*2+1] = o;
    }
    __syncthreads();

    int lane = t & 63, wid = t >> 6;
    const float NEGINF = -__builtin_inff();
    // 8 cells in flight per wave: cells e, e+4, ..., e+28 (stride 4 across 4 waves)
    for (int e = wid; e < 108; e += 32){
        unsigned cn_[8], o_[8], n_[8];
#pragma unroll
        for (int k = 0; k < 8; k++){
            int ek = e + k*4;
            bool hv = ek < 108;
            unsigned cc = hv ? cno[ek*2]   : NOCELL;
            unsigned oo = hv ? cno[ek*2+1] : 0;
            cn_[k] = cc;  o_[k] = oo;
            n_[k] = (cc == NOCELL) ? 0u : cc;
        }
        float m0[8], m1[8];
#pragma unroll
        for (int k = 0; k < 8; k++){ m0[k] = NEGINF; m1[k] = NEGINF; }
        unsigned nm = 0;
#pragma unroll
        for (int k = 0; k < 8; k++) nm = nm > n_[k] ? nm : n_[k];
        for (unsigned p = 0; p < nm; p++){
#pragma unroll
            for (int k = 0; k < 8; k++){
                if (p < n_[k]){
                    unsigned u = *(const unsigned*)(z4 + (size_t)(o_[k] + p)*256 + ch0 + lane*2);
                    m0[k] = fmaxf(m0[k], __uint_as_float(u << 16));
                    m1[k] = fmaxf(m1[k], __uint_as_float(u & 0xFFFF0000u));
                }
            }
        }
#pragma unroll
        for (int k = 0; k < 8; k++){
            int ek = e + k*4;
            if (ek < 108){
                float a0 = m0[k], a1 = m1[k];
                if (cn_[k] == 0u){ a0 = 0.f; a1 = 0.f; }
                *(unsigned*)&cm[ek*128 + lane*2] =
                    (__float_as_uint(a0) >> 16) | (__float_as_uint(a1) & 0xFFFF0000u);
            }
        }
    }
    __syncthreads();

    int c  = t & 127;
    int gp = t >> 7;
    float rA[2], rB[2];
    float ob[2][16];
#pragma unroll
    for (int gg = 0; gg < 2; gg++){ rA[gg] = 0.f; rB[gg] = 0.f; }
#pragma unroll
    for (int ty = 0; ty < 18; ty++){
        float v[6];
#pragma unroll
        for (int xx = 0; xx < 6; xx++)
            v[xx] = bf2f(cm[(xx*18 + ty)*128 + c]);
        float c3[2];
#pragma unroll
        for (int gg = 0; gg < 2; gg++){
            float va = (gp == 0) ? v[gg]     : v[gg+2];
            float vb = (gp == 0) ? v[gg+1]   : v[gg+3];
            float vc = (gp == 0) ? v[gg+2]   : v[gg+4];
            c3[gg] = fmaxf(fmaxf(va, vb), vc);
        }
        if (ty >= 2){
#pragma unroll
            for (int gg = 0; gg < 2; gg++)
                ob[gg][ty - 2] = fmaxf(fmaxf(rA[gg], rB[gg]), c3[gg]);
        }
#pragma unroll
        for (int gg = 0; gg < 2; gg++){ rA[gg] = rB[gg]; rB[gg] = c3[gg]; }
    }
    __syncthreads();

    unsigned short* ot = cm;
#pragma unroll
    for (int gg = 0; gg < 2; gg++){
        int g = gp*2 + gg;
#pragma unroll
        for (int yl = 0; yl < 16; yl++)
            ot[(g*16 + yl)*OTS + c] = (unsigned short)(__float_as_uint(ob[gg][yl]) >> 16);
    }
    __syncthreads();

    int rsub = lane >> 2;
    int gyq  = lane & 3;
    int y0   = gyq*4;
#pragma unroll
    for (int it = 0; it < 8; it++){
        int r  = wid*128 + it*16 + rsub;
        int gx = r >> 7;
        int c2 = r & 127;
        if (y0 < ymax){
            float4 o4;
            o4.x = bf2f(ot[(gx*16 + y0+0)*OTS + c2]);
            o4.y = bf2f(ot[(gx*16 + y0+1)*OTS + c2]);
            o4.z = bf2f(ot[(gx*16 + y0+2)*OTS + c2]);
            o4.w = bf2f(ot[(gx*16 + y0+3)*OTS + c2]);
            *(float4*)(out + ((size_t)b*258 + ch0 + c2)*GXY
                       + (size_t)(gx0+gx)*GYd + gy0 + y0) = o4;
        }
    }

    // residual channels for this tile (even-z blocks only)
    if ((bz & 1) == 0 && t < 128){
        int r  = t >> 6;                       // 0/1
        int g  = (t >> 4) & 3;                 // 0..3
        int y  = t & 15;
        if (y < ymax){
            unsigned u = pres[((size_t)b*2 + r)*GXY + (size_t)(gx0+g)*GYd + gy0 + y];
            float f = u ? unmapf(u) : 0.f;
            out[((size_t)b*258 + 256 + r)*GXY + (size_t)(gx0+g)*GYd + gy0 + y] = f;
        }
    }
}

extern "C" void kernel_launch(void* const* d_in, const int* in_sizes, int n_in,
                              void* d_out, int out_size, void* d_ws, size_t ws_size,
                              hipStream_t stream){
    (void)n_in; (void)out_size; (void)ws_size;
    const float* fea   = (const float*)d_in[0];
    const int*   ind   = (const int*)  d_in[1];
    const float* bn0_g = (const float*)d_in[2];
    const float* bn0_b = (const float*)d_in[3];
    const float* w1    = (const float*)d_in[4];
    const float* b1    = (const float*)d_in[5];
    const float* bn1_g = (const float*)d_in[6];
    const float* bn1_b = (const float*)d_in[7];
    const float* w2    = (const float*)d_in[8];
    const float* b2    = (const float*)d_in[9];
    const float* bn2_g = (const float*)d_in[10];
    const float* bn2_b = (const float*)d_in[11];
    const float* w3    = (const float*)d_in[12];
    const float* b3    = (const float*)d_in[13];
    const float* bn3_g = (const float*)d_in[14];
    const float* bn3_b = (const float*)d_in[15];
    const float* w4    = (const float*)d_in[16];
    const float* b4    = (const float*)d_in[17];

    int n = in_sizes[0] / 11;
    float invN = 1.0f / (float)n;

    // ---- ws layout ----
    const size_t Z4_B     = (size_t)240000*256*2;
    const size_t POOL_B   = (size_t)NCELL*256*2;        // arena for z1/z2/z3
    const size_t PRES_B   = (size_t)NBd*2*GXY*4;
    const size_t CNT_B    = (size_t)NCELL*4;
    const size_t STAT_B   = 960*4;
    const size_t GCTR_B   = 256;

    char* base = (char*)d_ws;
    unsigned short* z4 = (unsigned short*)base;
    unsigned short* z1 = (unsigned short*)(base + Z4_B);
    unsigned short* z2 = (unsigned short*)(base + Z4_B + 15360000);
    unsigned short* z3 = (unsigned short*)(base + Z4_B + 46080000);
    unsigned* pres  = (unsigned*)(base + Z4_B + POOL_B);
    unsigned* cnt   = (unsigned*)((char*)pres + PRES_B);
    float*    stats = (float*)((char*)cnt + CNT_B);
    unsigned* gctr  = (unsigned*)((char*)stats + STAT_B);
    unsigned* off   = (unsigned*)((char*)gctr + GCTR_B);
    unsigned* list  = (unsigned*)((char*)off + CNT_B);
    unsigned* rank  = (unsigned*)((char*)list + (size_t)240000*4);

    float* sum0 = stats;       float* sq0 = stats + 16;
    float* sum1 = stats + 32;  float* sq1 = stats + 64;
    float* sum2 = stats + 96;  float* sq2 = stats + 160;
    float* sum3 = stats + 224; float* sq3 = stats + 352;

    hipMemsetAsync(pres, 0, PRES_B + CNT_B + STAT_B + GCTR_B, stream);

    int nb = (n + 255) / 256;
    int nb512 = (n + 511) / 512;
    k_stats0<<<nb, 256, 0, stream>>>(fea, sum0, sq0, n);
    k_l1<<<nb, 256, 0, stream>>>(fea, ind, w1, b1, sum0, sq0, bn0_g, bn0_b, invN,
                                 z1, pres, cnt, rank, sum1, sq1, n);
    k_l2<<<nb512, 256, 0, stream>>>(z1, w2, b2, sum1, sq1, bn1_g, bn1_b, invN,
                                    z2, sum2, sq2, n);
    k_l3<<<nb512, 256, 0, stream>>>(z2, w3, b3, sum2, sq2, bn2_g, bn2_b, invN,
                                    z3, sum3, sq3, n);

    k_off <<<(NCELL + 1023)/1024, 256, 0, stream>>>(cnt, off, gctr);
    k_fill<<<nb, 256, 0, stream>>>(ind, rank, off, list, n);

    k_l4<<<nb512, 256, 0, stream>>>(z3, list, w4, b4, sum3, sq3, bn3_g, bn3_b, invN,
                                    z4, n);

    k_gpool<<<dim3(23, 120, 4), 256, 0, stream>>>(cnt, off, z4, pres, (float*)d_out);
}